// Round 1
// baseline (269.794 us; speedup 1.0000x reference)
//
#include <hip/hip_runtime.h>

#define SQRT5F 2.2360679774997896f

typedef float v4f __attribute__((ext_vector_type(4)));

// out[i,a,j,b] = c^2 * ( (a==b) * A(i,j) * inv_l2[a]  -  5*fr(i,j)*D[i,j,a]*D[i,j,b] )
// with D[i,j,k] = (X1[i,k]-X2[j,k]) * inv_l2[k]
//      r^2      = sum_k (X1[i,k]-X2[j,k])^2 * inv_l2[k]
//      fr       = (5/3) * exp(-sqrt5 * r)
//      A        = fr * (1 + sqrt5 * r)
//
// d hardcoded to 8. TWO threads per (i,j) pair: t>>1 = j-slot, t&1 = which
// half (4 floats) of each b-run this thread stores -> lane t stores at byte
// offset t*16 within the per-a run -> every store is 64 lanes x contiguous
// 16B = dense 1 KiB.
//
// v2 changes vs previous (256.6 us) version:
//  - each thread handles TWO j values (j0 and j0+128): prologue (uniform
//    loads, rcp/sqrt/exp chain) amortized 2x, and each wave issues 16
//    global_store_dwordx4 instead of 8 -> deeper sustained store queue.
//  - all output stores are nontemporal (evict-first): output is
//    write-once-never-read, don't let 268 MB of dead lines thrash the
//    32 MB L2.

__global__ __launch_bounds__(256) void deriv2_matern52_kernel(
    const float* __restrict__ X1,
    const float* __restrict__ X2,
    const float* __restrict__ c_ptr,
    const float* __restrict__ l_ptr,
    float* __restrict__ out,
    int m /* = 1024 */)
{
    const int t = threadIdx.x;
    const int jblocks = m >> 8;                 // 256 j per block, 2 per thread
    const int i  = blockIdx.x / jblocks;
    const int jb = blockIdx.x - i * jblocks;
    const int p  = t >> 1;                      // j-slot within block (0..127)
    const int h  = t & 1;                       // which half of the b-run
    const int b0 = h << 2;                      // 0 or 4

    const int j0 = (jb << 8) + p;               // second j is j0 + 128

    const float c  = c_ptr[0];
    const float c2 = c * c;

    // lengthscales -> 1/l^2 (wave-uniform; broadcast loads)
    float inv_l2[8];
#pragma unroll
    for (int k = 0; k < 8; ++k) {
        const float lv = l_ptr[k];
        inv_l2[k] = 1.0f / (lv * lv);
    }

    // X1 row (32B), shared by both pairs
    const float4 x1a = ((const float4*)(X1 + (size_t)i * 8))[0];
    const float4 x1b = ((const float4*)(X1 + (size_t)i * 8))[1];
    const float x1v[8] = { x1a.x, x1a.y, x1a.z, x1a.w,
                           x1b.x, x1b.y, x1b.z, x1b.w };

    // X2 rows for both j's (issued up front; independent loads)
    const float4 x2a0 = ((const float4*)(X2 + (size_t)j0 * 8))[0];
    const float4 x2b0 = ((const float4*)(X2 + (size_t)j0 * 8))[1];
    const float4 x2a1 = ((const float4*)(X2 + ((size_t)j0 + 128) * 8))[0];
    const float4 x2b1 = ((const float4*)(X2 + ((size_t)j0 + 128) * 8))[1];

    const float x2v0[8] = { x2a0.x, x2a0.y, x2a0.z, x2a0.w,
                            x2b0.x, x2b0.y, x2b0.z, x2b0.w };
    const float x2v1[8] = { x2a1.x, x2a1.y, x2a1.z, x2a1.w,
                            x2b1.x, x2b1.y, x2b1.z, x2b1.w };

    float D0[8], D1[8];
    float r20 = 0.0f, r21 = 0.0f;
#pragma unroll
    for (int k = 0; k < 8; ++k) {
        const float dx0 = x1v[k] - x2v0[k];
        const float dx1 = x1v[k] - x2v1[k];
        D0[k] = dx0 * inv_l2[k];
        D1[k] = dx1 * inv_l2[k];
        r20 += dx0 * D0[k];                      // dx^2 * inv_l2
        r21 += dx1 * D1[k];
    }

    const float r0  = sqrtf(r20);
    const float r1  = sqrtf(r21);
    const float fr0 = (5.0f / 3.0f) * expf(-SQRT5F * r0);
    const float fr1 = (5.0f / 3.0f) * expf(-SQRT5F * r1);
    const float A0  = fr0 * (1.0f + SQRT5F * r0);
    const float A1  = fr1 * (1.0f + SQRT5F * r1);

    const float Ac0 = A0 * c2;                   // diagonal coefficient
    const float Ac1 = A1 * c2;
    const float cf0 = -5.0f * fr0 * c2;          // pair coefficient
    const float cf1 = -5.0f * fr1 * c2;

    // this thread's 4 b-values per pair, pre-scaled (h-select, compiler
    // lowers to cndmask between D[0..3] and D[4..7])
    const float Db0[4] = { D0[b0 + 0], D0[b0 + 1], D0[b0 + 2], D0[b0 + 3] };
    const float Db1[4] = { D1[b0 + 0], D1[b0 + 1], D1[b0 + 2], D1[b0 + 3] };

    // out base for (i, a=0, j0, b=b0): i*8*m*8 + j0*8 + b0
    float* op0 = out + (size_t)i * (size_t)(8 * m * 8) + (size_t)j0 * 8 + b0;
    float* op1 = op0 + (size_t)128 * 8;          // j0+128 -> +4 KiB
    const size_t astride = (size_t)m * 8;        // stride between consecutive a

#pragma unroll
    for (int a = 0; a < 8; ++a) {
        const float Dca0 = cf0 * D0[a];
        const float Dca1 = cf1 * D1[a];
        float v0[4], v1[4];
#pragma unroll
        for (int k = 0; k < 4; ++k) {
            v0[k] = Dca0 * Db0[k];
            v1[k] = Dca1 * Db1[k];
        }
        // diagonal term lands in this thread's half iff h == a>>2, at
        // element a&3 (both compile-time under the unroll except the
        // h-compare -> one cndmask+add per a)
        const float dsel = (h == (a >> 2)) ? 1.0f : 0.0f;
        v0[a & 3] += dsel * (Ac0 * inv_l2[a]);
        v1[a & 3] += dsel * (Ac1 * inv_l2[a]);

        v4f w0 = { v0[0], v0[1], v0[2], v0[3] };
        v4f w1 = { v1[0], v1[1], v1[2], v1[3] };
        __builtin_nontemporal_store(w0, (v4f*)(op0 + (size_t)a * astride));
        __builtin_nontemporal_store(w1, (v4f*)(op1 + (size_t)a * astride));
    }
}

extern "C" void kernel_launch(void* const* d_in, const int* in_sizes, int n_in,
                              void* d_out, int out_size, void* d_ws, size_t ws_size,
                              hipStream_t stream) {
    const float* X1 = (const float*)d_in[0];
    const float* X2 = (const float*)d_in[1];
    const float* c  = (const float*)d_in[2];
    const float* l  = (const float*)d_in[3];
    float* out = (float*)d_out;

    const int d = in_sizes[3];        // 8
    const int n = in_sizes[0] / d;    // 1024
    const int m = in_sizes[1] / d;    // 1024

    const int jblocks = m >> 8;       // 256 j (512 thread-slots / 2) per block
    dim3 grid(n * jblocks);
    dim3 block(256);
    deriv2_matern52_kernel<<<grid, block, 0, stream>>>(X1, X2, c, l, out, m);
}

// Round 2
// 259.777 us; speedup vs baseline: 1.0386x; 1.0386x over previous
//
#include <hip/hip_runtime.h>

#define SQRT5F 2.2360679774997896f

// out[i,a,j,b] = c^2 * ( (a==b) * A(i,j) * inv_l2[a]  -  5*fr(i,j)*D[i,j,a]*D[i,j,b] )
// with D[i,j,k] = (X1[i,k]-X2[j,k]) * inv_l2[k]
//      r^2      = sum_k (X1[i,k]-X2[j,k])^2 * inv_l2[k]
//      fr       = (5/3) * exp(-sqrt5 * r)
//      A        = fr * (1 + sqrt5 * r)
//
// d hardcoded to 8. TWO threads per (i,j) pair: t>>1 = j-slot, t&1 = which
// half (4 floats) of each b-run this thread stores -> lane t stores at byte
// offset t*16 within the per-a run -> every store is 64 lanes x contiguous
// 16B = dense 1 KiB.
//
// v3: PERSISTENT blocks. v1's waves issued 8 stores then died; the
// correlated per-block prologues (arg loads -> X2 load -> rcp/sqrt/exp
// chain, ~600 cy) kept draining the store queue -> 3.0 TB/s vs fill's
// 6.4 TB/s. Now grid = 2048 blocks (8/CU, 32 waves/CU at <=64 VGPR);
// grid stride is a multiple of jblocks so j (and the X2 row, inv_l2, c2)
// is loop-invariant; each wave issues 32 stores, and the next iteration's
// X1 load + VALU overlaps the previous iteration's store drain.
// (v2's 2-j-per-thread + NT stores regressed 257.5 -> 269.8 us: reverted.)

__global__ __launch_bounds__(256) void deriv2_matern52_kernel(
    const float* __restrict__ X1,
    const float* __restrict__ X2,
    const float* __restrict__ c_ptr,
    const float* __restrict__ l_ptr,
    float* __restrict__ out,
    int m /* = 1024 */,
    int n /* = 1024 */,
    int jblocks /* = m>>7 */)
{
    const int t = threadIdx.x;
    const int h  = t & 1;                       // half of the 8-float b-run
    const int b0 = h << 2;                      // 0 or 4

    const int bid = blockIdx.x;
    const int jb  = bid % jblocks;              // invariant: gridDim.x % jblocks == 0
    const int i0  = bid / jblocks;
    const int istep = gridDim.x / jblocks;      // i advance per iteration
    const int j   = (jb << 7) + (t >> 1);

    const float c  = c_ptr[0];
    const float c2 = c * c;

    // lengthscales -> 1/l^2 (loop-invariant)
    float inv_l2[8];
#pragma unroll
    for (int k = 0; k < 8; ++k) {
        const float lv = l_ptr[k];
        inv_l2[k] = 1.0f / (lv * lv);
    }

    // X2 row (loop-invariant: j fixed for this block across all iterations)
    const float4 x2a = ((const float4*)(X2 + (size_t)j * 8))[0];
    const float4 x2b = ((const float4*)(X2 + (size_t)j * 8))[1];
    const float x2v[8] = { x2a.x, x2a.y, x2a.z, x2a.w,
                           x2b.x, x2b.y, x2b.z, x2b.w };

    const size_t astride = (size_t)m * 8;            // stride between consecutive a
    const size_t istride = (size_t)istep * 64 * m;   // out-advance per iteration
    float* op = out + (size_t)i0 * (size_t)(8 * m * 8) + (size_t)j * 8 + b0;

    for (int i = i0; i < n; i += istep, op += istride) {
        // X1 row (32B, wave-uniform broadcast; X1 is 32 KB total -> cache-hot)
        const float4 x1a = ((const float4*)(X1 + (size_t)i * 8))[0];
        const float4 x1b = ((const float4*)(X1 + (size_t)i * 8))[1];
        const float x1v[8] = { x1a.x, x1a.y, x1a.z, x1a.w,
                               x1b.x, x1b.y, x1b.z, x1b.w };

        float D[8];
        float r2 = 0.0f;
#pragma unroll
        for (int k = 0; k < 8; ++k) {
            const float dx = x1v[k] - x2v[k];
            D[k] = dx * inv_l2[k];
            r2 += dx * D[k];                     // dx^2 * inv_l2
        }

        const float r  = sqrtf(r2);
        const float fr = (5.0f / 3.0f) * expf(-SQRT5F * r);
        const float A  = fr * (1.0f + SQRT5F * r);

        const float Ac = A * c2;                 // diagonal coefficient
        const float cf = -5.0f * fr * c2;        // pair coefficient

        // this thread's 4 b-values (h-select -> cndmask, no memory)
        const float Db[4] = { D[b0 + 0], D[b0 + 1], D[b0 + 2], D[b0 + 3] };

#pragma unroll
        for (int a = 0; a < 8; ++a) {
            const float Dca = cf * D[a];
            float v[4];
#pragma unroll
            for (int k = 0; k < 4; ++k) v[k] = Dca * Db[k];
            // diagonal term lands in this thread's half iff h == a>>2,
            // at element a&3 (compile-time under the unroll)
            const float dsel = (h == (a >> 2)) ? 1.0f : 0.0f;
            v[a & 3] += dsel * (Ac * inv_l2[a]);

            *(float4*)(op + (size_t)a * astride) = make_float4(v[0], v[1], v[2], v[3]);
        }
    }
}

extern "C" void kernel_launch(void* const* d_in, const int* in_sizes, int n_in,
                              void* d_out, int out_size, void* d_ws, size_t ws_size,
                              hipStream_t stream) {
    const float* X1 = (const float*)d_in[0];
    const float* X2 = (const float*)d_in[1];
    const float* c  = (const float*)d_in[2];
    const float* l  = (const float*)d_in[3];
    float* out = (float*)d_out;

    const int d = in_sizes[3];        // 8
    const int n = in_sizes[0] / d;    // 1024
    const int m = in_sizes[1] / d;    // 1024

    const int jblocks = m >> 7;       // 128 pairs (256 threads) per j-block
    // Persistent grid: ~2048 blocks (8 blocks/CU -> 32 waves/CU), rounded
    // to a multiple of jblocks so each block's j-range is loop-invariant.
    int iper = 2048 / jblocks;        // i-values per grid sweep
    if (iper < 1) iper = 1;
    if (iper > n) iper = n;
    dim3 grid(jblocks * iper);
    dim3 block(256);
    deriv2_matern52_kernel<<<grid, block, 0, stream>>>(X1, X2, c, l, out, m, n, jblocks);
}